// Round 8
// baseline (349.224 us; speedup 1.0000x reference)
//
#include <hip/hip_runtime.h>

// ---------------------------------------------------------------------------
// AttentionMulti: x[4,2048,1024] fp32 -> qkv -> 16-head attention (D=64,
// scale=0.5, key-mask) -> out proj.  Inputs/outputs fp32, mask int32.
// Internal compute in bf16 MFMA.
// ---------------------------------------------------------------------------

typedef __bf16 bf16;
typedef __attribute__((ext_vector_type(8))) __bf16 bf16x8;
typedef __attribute__((ext_vector_type(4))) float f32x4;
typedef __attribute__((ext_vector_type(16))) float f32x16;

#define MFMA16(a, b, c) __builtin_amdgcn_mfma_f32_16x16x32_bf16(a, b, c, 0, 0, 0)
#define MFMA32(a, b, c) __builtin_amdgcn_mfma_f32_32x32x16_bf16(a, b, c, 0, 0, 0)

// ---------------------------------------------------------------------------
__global__ __launch_bounds__(256, 1) void cvt_f32_bf16(
    const float* __restrict__ in, bf16* __restrict__ out, int n4)
{
    int i = blockIdx.x * 256 + threadIdx.x;
    if (i >= n4) return;
    float4 v = *(const float4*)(in + (size_t)i * 4);
    union { ushort4 u; bf16 h[4]; } o;
    o.h[0] = (bf16)v.x; o.h[1] = (bf16)v.y; o.h[2] = (bf16)v.z; o.h[3] = (bf16)v.w;
    *(ushort4*)(out + (size_t)i * 4) = o.u;
}

// ---------------------------------------------------------------------------
__global__ __launch_bounds__(256, 1) void transpose_f32_bf16(
    const float* __restrict__ in, bf16* __restrict__ out, int R, int C)
{
    __shared__ float s[64][65];
    const int t  = threadIdx.x;
    const int r0 = blockIdx.y * 64;
    const int c0 = blockIdx.x * 64;
    const int tr  = t >> 4;
    const int tc4 = (t & 15) * 4;
#pragma unroll
    for (int p = 0; p < 4; ++p) {
        int r = tr + p * 16;
        float4 v = *(const float4*)(in + (size_t)(r0 + r) * C + c0 + tc4);
        s[r][tc4 + 0] = v.x; s[r][tc4 + 1] = v.y;
        s[r][tc4 + 2] = v.z; s[r][tc4 + 3] = v.w;
    }
    __syncthreads();
    const int cw  = t >> 3;
    const int rw8 = (t & 7) * 8;
#pragma unroll
    for (int p = 0; p < 2; ++p) {
        int c = cw + p * 32;
        union { uint4 v; bf16 h[8]; } u;
#pragma unroll
        for (int j = 0; j < 8; ++j) u.h[j] = (bf16)s[rw8 + j][c];
        *(uint4*)(out + (size_t)(c0 + c) * R + r0 + rw8) = u.v;
    }
}

// ---------------------------------------------------------------------------
// C[M][N] = A[M][K] @ Bt[N][K]^T + bias[N]   (m97-style 128x128 tile, BK=32)
// ---------------------------------------------------------------------------
template <typename OutT>
__global__ __launch_bounds__(256, 1) void gemm_bias_kernel(
    const bf16* __restrict__ A, const bf16* __restrict__ Bt,
    const float* __restrict__ bias, OutT* __restrict__ C,
    int M, int N, int K)
{
    __shared__ __align__(16) bf16 As[128 * 32];
    __shared__ __align__(16) bf16 Bs[128 * 32];
    const int t    = threadIdx.x;
    const int lane = t & 63;
    const int wave = t >> 6;
    const int l15  = lane & 15;
    const int g    = lane >> 4;
    const int m0   = blockIdx.y * 128;
    const int n0   = blockIdx.x * 128;
    const int wr   = (wave >> 1) * 64;
    const int wc   = (wave & 1) * 64;

    const f32x4 z = {0.f, 0.f, 0.f, 0.f};
    f32x4 acc[4][4];
#pragma unroll
    for (int i = 0; i < 4; ++i)
#pragma unroll
        for (int j = 0; j < 4; ++j) acc[i][j] = z;

    const int e0 = t * 8;

    for (int k0 = 0; k0 < K; k0 += 32) {
        __syncthreads();
#pragma unroll
        for (int rnd = 0; rnd < 2; ++rnd) {
            int e   = e0 + rnd * 2048;
            int row = e >> 5;
            int col = e & 31;
            __builtin_amdgcn_global_load_lds(
                (const __attribute__((address_space(1))) void*)(A + (size_t)(m0 + row) * K + k0 + col),
                (__attribute__((address_space(3))) void*)(As + e), 16, 0, 0);
            __builtin_amdgcn_global_load_lds(
                (const __attribute__((address_space(1))) void*)(Bt + (size_t)(n0 + row) * K + k0 + col),
                (__attribute__((address_space(3))) void*)(Bs + e), 16, 0, 0);
        }
        asm volatile("s_waitcnt vmcnt(0)" ::: "memory");
        __syncthreads();

        bf16x8 a[4], b[4];
#pragma unroll
        for (int i = 0; i < 4; ++i)
            a[i] = *(const bf16x8*)(As + (wr + i * 16 + l15) * 32 + g * 8);
#pragma unroll
        for (int j = 0; j < 4; ++j)
            b[j] = *(const bf16x8*)(Bs + (wc + j * 16 + l15) * 32 + g * 8);
#pragma unroll
        for (int i = 0; i < 4; ++i)
#pragma unroll
            for (int j = 0; j < 4; ++j)
                acc[i][j] = MFMA16(a[i], b[j], acc[i][j]);
    }

#pragma unroll
    for (int i = 0; i < 4; ++i) {
#pragma unroll
        for (int j = 0; j < 4; ++j) {
#pragma unroll
            for (int r = 0; r < 4; ++r) {
                int row = m0 + wr + i * 16 + g * 4 + r;
                int col = n0 + wc + j * 16 + l15;
                float v = acc[i][j][r] + bias[col];
                C[(size_t)row * N + col] = (OutT)v;
            }
        }
    }
}

// ---------------------------------------------------------------------------
// Attention v5.1: 32x32x16 MFMA (halves LDS bytes/FLOP vs 16x16).
//  ROUND-7 FIX: Ps row stride was 40 but rows hold 64 keys -> rows aliased
//  and fragment reads ran past the wave's Ps region (cross-wave garbage).
//  Ps/Vt stride now 66 (64 + 2 pad): total LDS 54.3 KB -> 3 blocks/CU.
//  - block = 128 q-rows, wave = 32 q-rows; 64-key chunks, 32 iterations.
//  - Ks/Vt double-buffered; one __syncthreads per chunk; global K/V prefetch
//    held in regs across the body.
//  - scale folded into Q; mask via zeroed V rows + indicator-B denominator.
// ---------------------------------------------------------------------------
__global__ __launch_bounds__(256, 3) void attn_kernel(
    const bf16* __restrict__ qkv, const int* __restrict__ mask,
    bf16* __restrict__ O)
{
    __shared__ __align__(16) bf16 Ks[2][64 * 64];   // 16 KB, xor-swizzled
    __shared__ __align__(16) bf16 Vt[2][64 * 66];   // 16.5 KB [d][key]
    __shared__ __align__(16) bf16 Ps[4][32 * 66];   // 16.5 KB per-wave P
    __shared__ __align__(16) bf16 maskb[2048];      //  4 KB indicator (1/0)

    const int t    = threadIdx.x;
    const int lane = t & 63;
    const int wave = t >> 6;
    const int l31  = lane & 31;
    const int hh   = lane >> 5;       // 0/1: k-half of A/B fragments

    const int bid = blockIdx.x;       // 0..1023
    const int qt  = bid & 15;
    const int bh  = bid >> 4;
    const int h   = bh & 15;
    const int b   = bh >> 4;
    const int q0  = qt * 128 + wave * 32;

    const int* mrow = mask + b * 2048;
    for (int i = t; i < 2048; i += 256)
        maskb[i] = mrow[i] ? (bf16)1.0f : (bf16)0.0f;

    const size_t RS = 3072;
    const float SC = 0.72134752f;     // 0.5 * log2(e), folded into Q

    // Q fragments (A-layout 32x32x16): m=l31, k = hh*8+j, 4 k-steps over d=64
    bf16x8 aQ[4];
    {
        const bf16* qp = qkv + (size_t)(b * 2048 + q0 + l31) * RS + h * 64 + hh * 8;
#pragma unroll
        for (int ds = 0; ds < 4; ++ds) {
            bf16x8 v = *(const bf16x8*)(qp + ds * 16);
#pragma unroll
            for (int j = 0; j < 8; ++j) v[j] = (bf16)((float)v[j] * SC);
            aQ[ds] = v;
        }
    }

    const bf16* kbase = qkv + (size_t)(b * 2048) * RS + 1024 + h * 64;
    const bf16* vbase = qkv + (size_t)(b * 2048) * RS + 2048 + h * 64;

    f32x16 o0, o1, lacc;
#pragma unroll
    for (int j = 0; j < 16; ++j) { o0[j] = 0.f; o1[j] = 0.f; lacc[j] = 0.f; }

    // --- staging geometry ---
    const int kkey = t >> 2;                    // K: key 0..63
    const int kc4  = t & 3;                     //    d-seg (2 x b128)
    const bf16* kp_t = kbase + (size_t)kkey * RS + kc4 * 16;
    const int kd0 = ((2 * kc4)     ^ (kkey & 7)) * 8;
    const int kd1 = ((2 * kc4 + 1) ^ (kkey & 7)) * 8;
    const int vrow = t & 63;                    // V: key
    const int vd   = (t >> 6) * 16;             //    d-range (wave-uniform)
    const bf16* vp_t = vbase + (size_t)vrow * RS + vd;

    union V16 { uint4 u[2]; bf16 h[16]; };

    // ---- prologue: stage chunk 0 into buffers[0] ----
    {
        uint4 k0 = *(const uint4*)(kp_t);
        uint4 k1 = *(const uint4*)(kp_t + 8);
        V16 v;
        v.u[0] = *(const uint4*)(vp_t);
        v.u[1] = *(const uint4*)(vp_t + 8);
        unsigned vm = mrow[vrow] ? 0xFFFFFFFFu : 0u;
        v.u[0].x &= vm; v.u[0].y &= vm; v.u[0].z &= vm; v.u[0].w &= vm;
        v.u[1].x &= vm; v.u[1].y &= vm; v.u[1].z &= vm; v.u[1].w &= vm;
        *(uint4*)(&Ks[0][kkey * 64 + kd0]) = k0;
        *(uint4*)(&Ks[0][kkey * 64 + kd1]) = k1;
#pragma unroll
        for (int j = 0; j < 16; ++j) Vt[0][(vd + j) * 66 + vrow] = v.h[j];
    }
    __syncthreads();

    for (int i = 0; i < 32; ++i) {
        const int kc  = i * 64;
        const int buf = i & 1;
        const bool more = (i + 1 < 32);

        // ---- global prefetch for chunk i+1 (consumed at tail) ----
        uint4 nk0, nk1;  V16 nv;  unsigned vm = 0;
        if (more) {
            const bf16* kp = kp_t + (size_t)(kc + 64) * RS;
            const bf16* vp = vp_t + (size_t)(kc + 64) * RS;
            nk0 = *(const uint4*)(kp);
            nk1 = *(const uint4*)(kp + 8);
            nv.u[0] = *(const uint4*)(vp);
            nv.u[1] = *(const uint4*)(vp + 8);
            vm = mrow[kc + 64 + vrow] ? 0xFFFFFFFFu : 0u;
        }

        // ---- S = Q_scaled K^T  (32 q x 64 keys, two 32-key n-tiles) ----
        f32x16 S0, S1;
#pragma unroll
        for (int j = 0; j < 16; ++j) { S0[j] = 0.f; S1[j] = 0.f; }
#pragma unroll
        for (int ds = 0; ds < 4; ++ds) {
            const int blk = ((ds * 2 + hh) ^ (l31 & 7)) * 8;
            bf16x8 bk0 = *(const bf16x8*)(&Ks[buf][(l31)      * 64 + blk]);
            bf16x8 bk1 = *(const bf16x8*)(&Ks[buf][(32 + l31) * 64 + blk]);
            S0 = MFMA32(aQ[ds], bk0, S0);
            S1 = MFMA32(aQ[ds], bk1, S1);
        }

        // ---- P = exp2(S)  -> per-wave Ps (C-layout scatter) ----
#pragma unroll
        for (int r = 0; r < 16; ++r) {
            const int row = (r & 3) + 8 * (r >> 2) + 4 * hh;
            Ps[wave][row * 66 + l31]      = (bf16)__builtin_amdgcn_exp2f(S0[r]);
            Ps[wave][row * 66 + 32 + l31] = (bf16)__builtin_amdgcn_exp2f(S1[r]);
        }
        asm volatile("s_waitcnt lgkmcnt(0)" ::: "memory");  // wave-local fence

        // ---- A-fragments of P (4 k-steps of 16 keys) ----
        bf16x8 aP[4];
#pragma unroll
        for (int ks = 0; ks < 4; ++ks)
            aP[ks] = *(const bf16x8*)(&Ps[wave][l31 * 66 + ks * 16 + hh * 8]);

        // ---- denominator: mask-broadcast B fragments ----
#pragma unroll
        for (int ks = 0; ks < 4; ++ks) {
            const bf16x8 mf = *(const bf16x8*)(&maskb[kc + ks * 16 + hh * 8]);
            lacc = MFMA32(aP[ks], mf, lacc);
        }

        // ---- PV: 2 d-tiles x 4 k-steps ----
#pragma unroll
        for (int ks = 0; ks < 4; ++ks) {
            bf16x8 bv0 = *(const bf16x8*)(&Vt[buf][(l31)      * 66 + ks * 16 + hh * 8]);
            bf16x8 bv1 = *(const bf16x8*)(&Vt[buf][(32 + l31) * 66 + ks * 16 + hh * 8]);
            o0 = MFMA32(aP[ks], bv0, o0);
            o1 = MFMA32(aP[ks], bv1, o1);
        }

        // ---- tail: commit chunk i+1 into the other buffers ----
        if (more) {
            *(uint4*)(&Ks[buf ^ 1][kkey * 64 + kd0]) = nk0;
            *(uint4*)(&Ks[buf ^ 1][kkey * 64 + kd1]) = nk1;
            nv.u[0].x &= vm; nv.u[0].y &= vm; nv.u[0].z &= vm; nv.u[0].w &= vm;
            nv.u[1].x &= vm; nv.u[1].y &= vm; nv.u[1].z &= vm; nv.u[1].w &= vm;
#pragma unroll
            for (int j = 0; j < 16; ++j) Vt[buf ^ 1][(vd + j) * 66 + vrow] = nv.h[j];
        }
        __syncthreads();   // single barrier per chunk
    }

    // ---- normalize + store ----
    float inv[16];
#pragma unroll
    for (int r = 0; r < 16; ++r) inv[r] = 1.0f / fmaxf(lacc[r], 1e-30f);

#pragma unroll
    for (int r = 0; r < 16; ++r) {
        const int row = q0 + (r & 3) + 8 * (r >> 2) + 4 * hh;
        bf16* op = O + (size_t)(b * 2048 + row) * 1024 + h * 64;
        op[l31]      = (bf16)(o0[r] * inv[r]);
        op[32 + l31] = (bf16)(o1[r] * inv[r]);
    }
}

// ---------------------------------------------------------------------------
extern "C" void kernel_launch(void* const* d_in, const int* in_sizes, int n_in,
                              void* d_out, int out_size, void* d_ws, size_t ws_size,
                              hipStream_t stream)
{
    const float* x     = (const float*)d_in[0];
    const int*   mask  = (const int*)d_in[1];
    const float* w_qkv = (const float*)d_in[2];
    const float* b_qkv = (const float*)d_in[3];
    const float* w_out = (const float*)d_in[4];
    const float* b_out = (const float*)d_in[5];
    float* out = (float*)d_out;

    char* ws = (char*)d_ws;
    bf16* qkvb  = (bf16*)(ws);                 // 48 MiB: [8192][3072]
    bf16* Obuf  = (bf16*)(ws + 50331648);      // 16 MiB: [8192][1024]
    bf16* xb    = (bf16*)(ws + 67108864);      // 16 MiB: [8192][1024]
    bf16* wqkvT = (bf16*)(ws + 83886080);      //  6 MiB: [3072][1024]
    bf16* woutT = (bf16*)(ws + 90177536);      //  2 MiB: [1024][1024]

    cvt_f32_bf16<<<dim3(8192), 256, 0, stream>>>(x, xb, 2097152);
    transpose_f32_bf16<<<dim3(48, 16), 256, 0, stream>>>(w_qkv, wqkvT, 1024, 3072);
    transpose_f32_bf16<<<dim3(16, 16), 256, 0, stream>>>(w_out, woutT, 1024, 1024);
    gemm_bias_kernel<bf16><<<dim3(24, 64), 256, 0, stream>>>(xb, wqkvT, b_qkv, qkvb, 8192, 3072, 1024);
    attn_kernel<<<dim3(1024), 256, 0, stream>>>(qkvb, mask, Obuf);
    gemm_bias_kernel<float><<<dim3(8, 64), 256, 0, stream>>>(Obuf, woutT, b_out, out, 8192, 1024, 1024);
}